// Round 4
// baseline (294.434 us; speedup 1.0000x reference)
//
#include <hip/hip_runtime.h>
#include <hip/hip_bf16.h>
#include <math.h>

#define BB 64
#define SS 2048
#define HH 512
#define VV 50257
#define KD 1024   // I + H
#define NSPLIT 32 // attn s-chunks per batch row
#define LCH 8     // log-softmax chunks per row
#define LPT 25    // elems per thread in lsm_partial
#define BK 64     // gemm K-chunk
#define NCHUNK (KD/BK)

typedef float f32x4 __attribute__((ext_vector_type(4)));
typedef __bf16 bf16x8 __attribute__((ext_vector_type(8)));
typedef __attribute__((address_space(3))) void lds_void;
typedef __attribute__((address_space(1))) const void glb_void;

__device__ __forceinline__ float dot4(float4 a, float4 b) {
  return a.x*b.x + a.y*b.y + a.z*b.z + a.w*b.w;
}

__device__ __forceinline__ bf16x8 cvt8(float4 a, float4 b) {
  bf16x8 r;
  r[0]=(__bf16)a.x; r[1]=(__bf16)a.y; r[2]=(__bf16)a.z; r[3]=(__bf16)a.w;
  r[4]=(__bf16)b.x; r[5]=(__bf16)b.y; r[6]=(__bf16)b.z; r[7]=(__bf16)b.w;
  return r;
}

// ---------------------------------------------------------------------------
// Kernel A: fused scores+softmax+context partials. Group-of-4 online softmax.
// ---------------------------------------------------------------------------
__global__ __launch_bounds__(256) void attn_partial(
    const float* __restrict__ hprev, const float* __restrict__ enc,
    float* __restrict__ pm, float* __restrict__ pl, float* __restrict__ pacc)
{
  const int b = blockIdx.x >> 5;
  const int split = blockIdx.x & 31;
  const int t = threadIdx.x;
  const int w = t >> 6, lane = t & 63;

  const float* hb = hprev + b*HH + lane*8;
  const float4 h0 = *(const float4*)hb;
  const float4 h1 = *(const float4*)(hb + 4);

  float m = -INFINITY, lsum = 0.f;
  float acc[8];
#pragma unroll
  for (int j = 0; j < 8; ++j) acc[j] = 0.f;

  const int s0 = split*64 + w*16;
#pragma unroll
  for (int g = 0; g < 4; ++g) {
    const float* ep0 = enc + ((size_t)(s0 + g*4 + 0)*BB + b)*HH + lane*8;
    const float* ep1 = enc + ((size_t)(s0 + g*4 + 1)*BB + b)*HH + lane*8;
    const float* ep2 = enc + ((size_t)(s0 + g*4 + 2)*BB + b)*HH + lane*8;
    const float* ep3 = enc + ((size_t)(s0 + g*4 + 3)*BB + b)*HH + lane*8;
    const float4 e0a = *(const float4*)ep0, e0b = *(const float4*)(ep0+4);
    const float4 e1a = *(const float4*)ep1, e1b = *(const float4*)(ep1+4);
    const float4 e2a = *(const float4*)ep2, e2b = *(const float4*)(ep2+4);
    const float4 e3a = *(const float4*)ep3, e3b = *(const float4*)(ep3+4);

    float d0 = dot4(h0,e0a) + dot4(h1,e0b);
    float d1 = dot4(h0,e1a) + dot4(h1,e1b);
    float d2 = dot4(h0,e2a) + dot4(h1,e2b);
    float d3 = dot4(h0,e3a) + dot4(h1,e3b);
#pragma unroll
    for (int off = 32; off >= 1; off >>= 1) {
      d0 += __shfl_xor(d0, off, 64);
      d1 += __shfl_xor(d1, off, 64);
      d2 += __shfl_xor(d2, off, 64);
      d3 += __shfl_xor(d3, off, 64);
    }
    const float gm = fmaxf(fmaxf(d0,d1), fmaxf(d2,d3));
    const float mn = fmaxf(m, gm);
    const float sc = __expf(m - mn);
    const float p0 = __expf(d0 - mn), p1 = __expf(d1 - mn);
    const float p2 = __expf(d2 - mn), p3 = __expf(d3 - mn);
    lsum = lsum*sc + ((p0+p1) + (p2+p3));
    acc[0] = acc[0]*sc + p0*e0a.x + p1*e1a.x + p2*e2a.x + p3*e3a.x;
    acc[1] = acc[1]*sc + p0*e0a.y + p1*e1a.y + p2*e2a.y + p3*e3a.y;
    acc[2] = acc[2]*sc + p0*e0a.z + p1*e1a.z + p2*e2a.z + p3*e3a.z;
    acc[3] = acc[3]*sc + p0*e0a.w + p1*e1a.w + p2*e2a.w + p3*e3a.w;
    acc[4] = acc[4]*sc + p0*e0b.x + p1*e1b.x + p2*e2b.x + p3*e3b.x;
    acc[5] = acc[5]*sc + p0*e0b.y + p1*e1b.y + p2*e2b.y + p3*e3b.y;
    acc[6] = acc[6]*sc + p0*e0b.z + p1*e1b.z + p2*e2b.z + p3*e3b.z;
    acc[7] = acc[7]*sc + p0*e0b.w + p1*e1b.w + p2*e2b.w + p3*e3b.w;
    m = mn;
  }

  __shared__ float sm4[4], sl4[4];
  __shared__ float sacc[4][HH];
  if (lane == 0) { sm4[w] = m; sl4[w] = lsum; }
  __syncthreads();
  const float M = fmaxf(fmaxf(sm4[0], sm4[1]), fmaxf(sm4[2], sm4[3]));
  const float ew = __expf(m - M);
#pragma unroll
  for (int j = 0; j < 8; ++j) sacc[w][lane*8 + j] = acc[j]*ew;
  __syncthreads();

  const int rec = blockIdx.x;
  for (int hh = t; hh < HH; hh += 256)
    pacc[(size_t)rec*HH + hh] = sacc[0][hh]+sacc[1][hh]+sacc[2][hh]+sacc[3][hh];
  if (t == 0) {
    float L = sl4[0]*__expf(sm4[0]-M) + sl4[1]*__expf(sm4[1]-M)
            + sl4[2]*__expf(sm4[2]-M) + sl4[3]*__expf(sm4[3]-M);
    pm[rec] = M; pl[rec] = L;
  }
}

// ---------------------------------------------------------------------------
// Kernel B: combine NSPLIT partials per b -> context (bf16) -> featb[b][512+..]
// ---------------------------------------------------------------------------
__global__ __launch_bounds__(256) void attn_reduce(
    const float* __restrict__ pm, const float* __restrict__ pl,
    const float* __restrict__ pacc, __hip_bfloat16* __restrict__ featb)
{
  const int b = blockIdx.x, t = threadIdx.x;
  __shared__ float smm[NSPLIT], sll[NSPLIT], sco[NSPLIT];
  if (t < NSPLIT) { smm[t] = pm[b*NSPLIT + t]; sll[t] = pl[b*NSPLIT + t]; }
  __syncthreads();
  float M = -INFINITY;
  for (int q = 0; q < NSPLIT; ++q) M = fmaxf(M, smm[q]);
  float L = 0.f;
  for (int q = 0; q < NSPLIT; ++q) L += sll[q]*__expf(smm[q]-M);
  const float inv = 1.f/L;
  if (t < NSPLIT) sco[t] = __expf(smm[t]-M)*inv;
  __syncthreads();
  for (int hh = t; hh < HH; hh += 256) {
    float s = 0.f;
    for (int q = 0; q < NSPLIT; ++q)
      s += pacc[((size_t)b*NSPLIT + q)*HH + hh]*sco[q];
    featb[b*KD + HH + hh] = (__hip_bfloat16)s;
  }
}

// ---------------------------------------------------------------------------
// Kernel C: GRU gates as MFMA GEMM (3 source segments). Weights read once.
// ---------------------------------------------------------------------------
__global__ __launch_bounds__(256) void gru_gemm(
    const int* __restrict__ last_out, const float* __restrict__ emb,
    const float* __restrict__ hprev, const __hip_bfloat16* __restrict__ featb,
    const float* __restrict__ W_ih, const float* __restrict__ W_hh,
    float* __restrict__ gates)  // [3][BB][1536]
{
  const int gt  = blockIdx.x / 3;
  const int seg = blockIdx.x % 3;
  const int w = threadIdx.x >> 6, lane = threadIdx.x & 63;
  const int col = lane & 15, kg = lane >> 4;
  const int g = gt*64 + w*16 + col;

  const float* wrow = (seg == 2) ? (W_hh + (size_t)g*HH)
                                 : (W_ih + (size_t)g*KD + seg*HH);

  int lo_r[4];
#pragma unroll
  for (int mt = 0; mt < 4; ++mt) lo_r[mt] = last_out[mt*16 + col];

  f32x4 acc[4];
#pragma unroll
  for (int mt = 0; mt < 4; ++mt) acc[mt] = (f32x4){0.f,0.f,0.f,0.f};

  for (int k0 = 0; k0 < HH; k0 += 32) {
    const float* wp = wrow + k0 + kg*8;
    const bf16x8 bf = cvt8(*(const float4*)wp, *(const float4*)(wp+4));
#pragma unroll
    for (int mt = 0; mt < 4; ++mt) {
      const int bb = mt*16 + col;
      bf16x8 af;
      if (seg == 0) {
        const float* ap = emb + (size_t)lo_r[mt]*HH + k0 + kg*8;
        af = cvt8(*(const float4*)ap, *(const float4*)(ap+4));
      } else if (seg == 1) {
        af = *(const bf16x8*)(featb + (size_t)bb*KD + HH + k0 + kg*8);
      } else {
        const float* ap = hprev + (size_t)bb*HH + k0 + kg*8;
        af = cvt8(*(const float4*)ap, *(const float4*)(ap+4));
      }
      acc[mt] = __builtin_amdgcn_mfma_f32_16x16x32_bf16(af, bf, acc[mt], 0, 0, 0);
    }
  }

  float* gp = gates + (size_t)seg*BB*1536;
#pragma unroll
  for (int mt = 0; mt < 4; ++mt)
#pragma unroll
    for (int reg = 0; reg < 4; ++reg) {
      const int brow = mt*16 + kg*4 + reg;
      gp[(size_t)brow*1536 + g] = acc[mt][reg];
    }
}

// ---------------------------------------------------------------------------
// Kernel C2: GRU pointwise.
// ---------------------------------------------------------------------------
__global__ __launch_bounds__(512) void gru_pointwise(
    const float* __restrict__ gates, const float* __restrict__ hprev,
    const float* __restrict__ b_ih, const float* __restrict__ b_hh,
    float* __restrict__ hid_out, __hip_bfloat16* __restrict__ featb)
{
  const int b = blockIdx.x, j = threadIdx.x;
  const float* g0 = gates + (size_t)b*1536;
  const float* g1 = gates + (size_t)(BB + b)*1536;
  const float* g2 = gates + (size_t)(2*BB + b)*1536;

  const float i_r = g0[j]        + g1[j];
  const float i_z = g0[HH + j]   + g1[HH + j];
  const float i_n = g0[2*HH + j] + g1[2*HH + j];

  const float r = 1.f/(1.f + __expf(-(i_r + g2[j] + b_ih[j] + b_hh[j])));
  const float z = 1.f/(1.f + __expf(-(i_z + g2[HH+j] + b_ih[HH+j] + b_hh[HH+j])));
  const float n = tanhf(i_n + b_ih[2*HH+j] + r*(g2[2*HH+j] + b_hh[2*HH+j]));
  const float hp = hprev[b*HH + j];
  const float hn = (1.f - z)*n + z*hp;
  hid_out[b*HH + j] = hn;
  featb[(size_t)b*KD + j] = (__hip_bfloat16)hn;
}

// ---------------------------------------------------------------------------
// Kernel D: logits = featb @ W_out^T + b_out.
// W staged f32 into double-buffered LDS via global_load_lds (deep DMA queue,
// zero VGPR cost). Wave w owns b-rows w*16..w*16+15 and ALL 64 v of the tile
// (A-frag loaded once per k-slice -> 4x less featb L2 traffic).
// ---------------------------------------------------------------------------
__global__ __launch_bounds__(256) void logits_gemm(
    const __hip_bfloat16* __restrict__ featb, const float* __restrict__ W_out,
    const float* __restrict__ b_out, float* __restrict__ out)
{
  __shared__ float wtile[2][BK*64];   // [buf][row*64 + k], 16 KB each
  const int w = threadIdx.x >> 6, lane = threadIdx.x & 63;
  const int col = lane & 15, kg = lane >> 4;
  const int vbase = blockIdx.x*64;

  f32x4 acc[4];
#pragma unroll
  for (int nt = 0; nt < 4; ++nt) acc[nt] = (f32x4){0.f,0.f,0.f,0.f};

  // ---- stage one 64x64 f32 W chunk into LDS (wave w -> tile rows 16w..16w+15)
  auto stage = [&](int buf, int kc) {
#pragma unroll
    for (int i = 0; i < 4; ++i) {
      const int s = w*4 + i;                 // segment = 4 tile-rows
      const int row = 4*s + (lane >> 4);     // tile row this lane feeds
      int grow = vbase + row; if (grow > VV-1) grow = VV-1;
      const float* gp = W_out + (size_t)grow*KD + kc*BK + (lane & 15)*4;
      __builtin_amdgcn_global_load_lds((glb_void*)gp,
          (lds_void*)(&wtile[buf][s*256]), 16, 0, 0);
    }
  };

  stage(0, 0);
  __syncthreads();

  for (int kc = 0; kc < NCHUNK; ++kc) {
    if (kc + 1 < NCHUNK) stage((kc+1) & 1, kc+1);
    const float* wt = &wtile[kc & 1][0];
#pragma unroll
    for (int k0l = 0; k0l < BK; k0l += 32) {
      const bf16x8 af = *(const bf16x8*)(featb + (size_t)(w*16 + col)*KD
                                         + kc*BK + k0l + kg*8);
#pragma unroll
      for (int nt = 0; nt < 4; ++nt) {
        const float* lp = wt + (nt*16 + col)*BK + k0l + kg*8;
        const bf16x8 bf = cvt8(*(const float4*)lp, *(const float4*)(lp+4));
        acc[nt] = __builtin_amdgcn_mfma_f32_16x16x32_bf16(af, bf, acc[nt], 0, 0, 0);
      }
    }
    __syncthreads();
  }

#pragma unroll
  for (int nt = 0; nt < 4; ++nt) {
    const int v = vbase + nt*16 + col;
    if (v < VV) {
      const float bo = b_out[v];
#pragma unroll
      for (int reg = 0; reg < 4; ++reg) {
        const int brow = w*16 + kg*4 + reg;
        out[(size_t)brow*VV + v] = acc[nt][reg] + bo;
      }
    }
  }
}

// ---------------------------------------------------------------------------
// Kernel E1: per-(row,chunk) max/expsum, two-pass in registers.
// ---------------------------------------------------------------------------
__global__ __launch_bounds__(256) void lsm_partial(
    const float* __restrict__ out, float* __restrict__ pm2, float* __restrict__ pl2)
{
  const int b = blockIdx.x >> 3, ch = blockIdx.x & (LCH-1);
  const int t = threadIdx.x;
  const float* p = out + (size_t)b*VV;
  const int beg = ch*(256*LPT);

  float r[LPT];
#pragma unroll
  for (int i = 0; i < LPT; ++i) {
    const int idx = beg + t + i*256;
    r[i] = (idx < VV) ? p[idx] : -INFINITY;
  }
  float m = r[0];
#pragma unroll
  for (int i = 1; i < LPT; ++i) m = fmaxf(m, r[i]);
  float l = 0.f;
#pragma unroll
  for (int i = 0; i < LPT; ++i) l += __expf(r[i] - m);

#pragma unroll
  for (int off = 32; off >= 1; off >>= 1) {
    const float m2 = __shfl_xor(m, off, 64), l2 = __shfl_xor(l, off, 64);
    const float mn = fmaxf(m, m2);
    l = l*__expf(m - mn) + l2*__expf(m2 - mn);
    m = mn;
  }
  __shared__ float sm[4], sl[4];
  const int w = t >> 6, lane = t & 63;
  if (lane == 0) { sm[w] = m; sl[w] = l; }
  __syncthreads();
  if (t == 0) {
    float M = sm[0], L = sl[0];
#pragma unroll
    for (int q = 1; q < 4; ++q) {
      const float mn = fmaxf(M, sm[q]);
      L = L*__expf(M - mn) + sl[q]*__expf(sm[q] - mn);
      M = mn;
    }
    pm2[blockIdx.x] = M; pl2[blockIdx.x] = L;
  }
}

// ---------------------------------------------------------------------------
// Kernel E2: logits -= c[row]; c from the 8 partials.
// ---------------------------------------------------------------------------
__global__ __launch_bounds__(256) void lsm_sub(
    float* __restrict__ out, const float* __restrict__ pm2,
    const float* __restrict__ pl2)
{
  const int t = threadIdx.x;
  const size_t off = (size_t)blockIdx.x * 1024;
  const size_t total = (size_t)BB*VV;
  __shared__ float cs[2];
  __shared__ int rowA_s;
  if (t < 2) {
    size_t pos = (t == 0) ? off : (off + 1023 < total ? off + 1023 : total - 1);
    const int row = (int)(pos / VV);
    float M = -INFINITY, L = 0.f;
#pragma unroll
    for (int q = 0; q < LCH; ++q) {
      const float mq = pm2[row*LCH + q], lq = pl2[row*LCH + q];
      const float mn = fmaxf(M, mq);
      L = L*__expf(M - mn) + lq*__expf(mq - mn);
      M = mn;
    }
    cs[t] = M + logf(L);
    if (t == 0) rowA_s = row;
  }
  __syncthreads();

  const size_t i = off + (size_t)t*4;
  if (i >= total) return;
  const size_t rs = (size_t)(rowA_s + 1)*VV;
  float4 v = *(float4*)(out + i);
  v.x -= (i     >= rs) ? cs[1] : cs[0];
  v.y -= (i + 1 >= rs) ? cs[1] : cs[0];
  v.z -= (i + 2 >= rs) ? cs[1] : cs[0];
  v.w -= (i + 3 >= rs) ? cs[1] : cs[0];
  *(float4*)(out + i) = v;
}

// ---------------------------------------------------------------------------
extern "C" void kernel_launch(void* const* d_in, const int* in_sizes, int n_in,
                              void* d_out, int out_size, void* d_ws, size_t ws_size,
                              hipStream_t stream)
{
  const int*   last_output = (const int*)d_in[0];
  const float* last_hidden = (const float*)d_in[1];
  const float* enc         = (const float*)d_in[2];
  const float* emb         = (const float*)d_in[3];
  const float* W_ih        = (const float*)d_in[4];
  const float* b_ih        = (const float*)d_in[5];
  const float* W_hh        = (const float*)d_in[6];
  const float* b_hh        = (const float*)d_in[7];
  const float* W_out       = (const float*)d_in[8];
  const float* b_out       = (const float*)d_in[9];
  float* out = (float*)d_out;

  __hip_bfloat16* featb = (__hip_bfloat16*)d_ws;            // 64x1024 bf16
  float* gates = (float*)((char*)d_ws + (size_t)BB*KD*2);   // 3x64x1536 f32
  float* pm   = gates + (size_t)3*BB*1536;
  float* pl   = pm + BB*NSPLIT;
  float* pm2  = pl + BB*NSPLIT;
  float* pl2  = pm2 + BB*LCH;
  float* pacc = out;  // 4 MB parked in dead logits region

  float* logits  = out;
  float* hid_out = out + (size_t)BB*VV;

  attn_partial <<<dim3(BB*NSPLIT), dim3(256), 0, stream>>>(last_hidden, enc, pm, pl, pacc);
  attn_reduce  <<<dim3(BB),        dim3(256), 0, stream>>>(pm, pl, pacc, featb);
  gru_gemm     <<<dim3(24*3),      dim3(256), 0, stream>>>(last_output, emb, last_hidden,
                                                           featb, W_ih, W_hh, gates);
  gru_pointwise<<<dim3(BB),        dim3(512), 0, stream>>>(gates, last_hidden, b_ih, b_hh,
                                                           hid_out, featb);
  logits_gemm  <<<dim3((VV+63)/64), dim3(256), 0, stream>>>(featb, W_out, b_out, logits);
  lsm_partial  <<<dim3(BB*LCH),    dim3(256), 0, stream>>>(logits, pm2, pl2);
  lsm_sub      <<<dim3((int)(((size_t)BB*VV + 1023)/1024)), dim3(256), 0, stream>>>(logits, pm2, pl2);
}

// Round 5
// 215.013 us; speedup vs baseline: 1.3694x; 1.3694x over previous
//
#include <hip/hip_runtime.h>
#include <hip/hip_bf16.h>
#include <math.h>

#define BB 64
#define SS 2048
#define HH 512
#define VV 50257
#define KD 1024   // I + H
#define NSPLIT 32 // attn s-chunks per batch row
#define LCH 8     // log-softmax chunks per row
#define LPT 25    // elems per thread in lsm_partial

typedef float f32x4 __attribute__((ext_vector_type(4)));
typedef __bf16 bf16x8 __attribute__((ext_vector_type(8)));

__device__ __forceinline__ float dot4(float4 a, float4 b) {
  return a.x*b.x + a.y*b.y + a.z*b.z + a.w*b.w;
}

__device__ __forceinline__ bf16x8 cvt8(float4 a, float4 b) {
  bf16x8 r;
  r[0]=(__bf16)a.x; r[1]=(__bf16)a.y; r[2]=(__bf16)a.z; r[3]=(__bf16)a.w;
  r[4]=(__bf16)b.x; r[5]=(__bf16)b.y; r[6]=(__bf16)b.z; r[7]=(__bf16)b.w;
  return r;
}

// ---------------------------------------------------------------------------
// Kernel A: fused scores+softmax+context partials. Group-of-4 online softmax.
// ---------------------------------------------------------------------------
__global__ __launch_bounds__(256) void attn_partial(
    const float* __restrict__ hprev, const float* __restrict__ enc,
    float* __restrict__ pm, float* __restrict__ pl, float* __restrict__ pacc)
{
  const int b = blockIdx.x >> 5;
  const int split = blockIdx.x & 31;
  const int t = threadIdx.x;
  const int w = t >> 6, lane = t & 63;

  const float* hb = hprev + b*HH + lane*8;
  const float4 h0 = *(const float4*)hb;
  const float4 h1 = *(const float4*)(hb + 4);

  float m = -INFINITY, lsum = 0.f;
  float acc[8];
#pragma unroll
  for (int j = 0; j < 8; ++j) acc[j] = 0.f;

  const int s0 = split*64 + w*16;
#pragma unroll
  for (int g = 0; g < 4; ++g) {
    const float* ep0 = enc + ((size_t)(s0 + g*4 + 0)*BB + b)*HH + lane*8;
    const float* ep1 = enc + ((size_t)(s0 + g*4 + 1)*BB + b)*HH + lane*8;
    const float* ep2 = enc + ((size_t)(s0 + g*4 + 2)*BB + b)*HH + lane*8;
    const float* ep3 = enc + ((size_t)(s0 + g*4 + 3)*BB + b)*HH + lane*8;
    const float4 e0a = *(const float4*)ep0, e0b = *(const float4*)(ep0+4);
    const float4 e1a = *(const float4*)ep1, e1b = *(const float4*)(ep1+4);
    const float4 e2a = *(const float4*)ep2, e2b = *(const float4*)(ep2+4);
    const float4 e3a = *(const float4*)ep3, e3b = *(const float4*)(ep3+4);

    float d0 = dot4(h0,e0a) + dot4(h1,e0b);
    float d1 = dot4(h0,e1a) + dot4(h1,e1b);
    float d2 = dot4(h0,e2a) + dot4(h1,e2b);
    float d3 = dot4(h0,e3a) + dot4(h1,e3b);
#pragma unroll
    for (int off = 32; off >= 1; off >>= 1) {
      d0 += __shfl_xor(d0, off, 64);
      d1 += __shfl_xor(d1, off, 64);
      d2 += __shfl_xor(d2, off, 64);
      d3 += __shfl_xor(d3, off, 64);
    }
    const float gm = fmaxf(fmaxf(d0,d1), fmaxf(d2,d3));
    const float mn = fmaxf(m, gm);
    const float sc = __expf(m - mn);
    const float p0 = __expf(d0 - mn), p1 = __expf(d1 - mn);
    const float p2 = __expf(d2 - mn), p3 = __expf(d3 - mn);
    lsum = lsum*sc + ((p0+p1) + (p2+p3));
    acc[0] = acc[0]*sc + p0*e0a.x + p1*e1a.x + p2*e2a.x + p3*e3a.x;
    acc[1] = acc[1]*sc + p0*e0a.y + p1*e1a.y + p2*e2a.y + p3*e3a.y;
    acc[2] = acc[2]*sc + p0*e0a.z + p1*e1a.z + p2*e2a.z + p3*e3a.z;
    acc[3] = acc[3]*sc + p0*e0a.w + p1*e1a.w + p2*e2a.w + p3*e3a.w;
    acc[4] = acc[4]*sc + p0*e0b.x + p1*e1b.x + p2*e2b.x + p3*e3b.x;
    acc[5] = acc[5]*sc + p0*e0b.y + p1*e1b.y + p2*e2b.y + p3*e3b.y;
    acc[6] = acc[6]*sc + p0*e0b.z + p1*e1b.z + p2*e2b.z + p3*e3b.z;
    acc[7] = acc[7]*sc + p0*e0b.w + p1*e1b.w + p2*e2b.w + p3*e3b.w;
    m = mn;
  }

  __shared__ float sm4[4], sl4[4];
  __shared__ float sacc[4][HH];
  if (lane == 0) { sm4[w] = m; sl4[w] = lsum; }
  __syncthreads();
  const float M = fmaxf(fmaxf(sm4[0], sm4[1]), fmaxf(sm4[2], sm4[3]));
  const float ew = __expf(m - M);
#pragma unroll
  for (int j = 0; j < 8; ++j) sacc[w][lane*8 + j] = acc[j]*ew;
  __syncthreads();

  const int rec = blockIdx.x;
  for (int hh = t; hh < HH; hh += 256)
    pacc[(size_t)rec*HH + hh] = sacc[0][hh]+sacc[1][hh]+sacc[2][hh]+sacc[3][hh];
  if (t == 0) {
    float L = sl4[0]*__expf(sm4[0]-M) + sl4[1]*__expf(sm4[1]-M)
            + sl4[2]*__expf(sm4[2]-M) + sl4[3]*__expf(sm4[3]-M);
    pm[rec] = M; pl[rec] = L;
  }
}

// ---------------------------------------------------------------------------
// Kernel B: combine NSPLIT partials per b -> context (bf16) -> featb[b][512+..]
// ---------------------------------------------------------------------------
__global__ __launch_bounds__(256) void attn_reduce(
    const float* __restrict__ pm, const float* __restrict__ pl,
    const float* __restrict__ pacc, __hip_bfloat16* __restrict__ featb)
{
  const int b = blockIdx.x, t = threadIdx.x;
  __shared__ float smm[NSPLIT], sll[NSPLIT], sco[NSPLIT];
  if (t < NSPLIT) { smm[t] = pm[b*NSPLIT + t]; sll[t] = pl[b*NSPLIT + t]; }
  __syncthreads();
  float M = -INFINITY;
  for (int q = 0; q < NSPLIT; ++q) M = fmaxf(M, smm[q]);
  float L = 0.f;
  for (int q = 0; q < NSPLIT; ++q) L += sll[q]*__expf(smm[q]-M);
  const float inv = 1.f/L;
  if (t < NSPLIT) sco[t] = __expf(smm[t]-M)*inv;
  __syncthreads();
  for (int hh = t; hh < HH; hh += 256) {
    float s = 0.f;
    for (int q = 0; q < NSPLIT; ++q)
      s += pacc[((size_t)b*NSPLIT + q)*HH + hh]*sco[q];
    featb[b*KD + HH + hh] = (__hip_bfloat16)s;
  }
}

// ---------------------------------------------------------------------------
// Kernel C: GRU gates as MFMA GEMM (3 source segments). Weights read once.
// ---------------------------------------------------------------------------
__global__ __launch_bounds__(256) void gru_gemm(
    const int* __restrict__ last_out, const float* __restrict__ emb,
    const float* __restrict__ hprev, const __hip_bfloat16* __restrict__ featb,
    const float* __restrict__ W_ih, const float* __restrict__ W_hh,
    float* __restrict__ gates)  // [3][BB][1536]
{
  const int gt  = blockIdx.x / 3;
  const int seg = blockIdx.x % 3;
  const int w = threadIdx.x >> 6, lane = threadIdx.x & 63;
  const int col = lane & 15, kg = lane >> 4;
  const int g = gt*64 + w*16 + col;

  const float* wrow = (seg == 2) ? (W_hh + (size_t)g*HH)
                                 : (W_ih + (size_t)g*KD + seg*HH);

  int lo_r[4];
#pragma unroll
  for (int mt = 0; mt < 4; ++mt) lo_r[mt] = last_out[mt*16 + col];

  f32x4 acc[4];
#pragma unroll
  for (int mt = 0; mt < 4; ++mt) acc[mt] = (f32x4){0.f,0.f,0.f,0.f};

  for (int k0 = 0; k0 < HH; k0 += 32) {
    const float* wp = wrow + k0 + kg*8;
    const bf16x8 bf = cvt8(*(const float4*)wp, *(const float4*)(wp+4));
#pragma unroll
    for (int mt = 0; mt < 4; ++mt) {
      const int bb = mt*16 + col;
      bf16x8 af;
      if (seg == 0) {
        const float* ap = emb + (size_t)lo_r[mt]*HH + k0 + kg*8;
        af = cvt8(*(const float4*)ap, *(const float4*)(ap+4));
      } else if (seg == 1) {
        af = *(const bf16x8*)(featb + (size_t)bb*KD + HH + k0 + kg*8);
      } else {
        const float* ap = hprev + (size_t)bb*HH + k0 + kg*8;
        af = cvt8(*(const float4*)ap, *(const float4*)(ap+4));
      }
      acc[mt] = __builtin_amdgcn_mfma_f32_16x16x32_bf16(af, bf, acc[mt], 0, 0, 0);
    }
  }

  float* gp = gates + (size_t)seg*BB*1536;
#pragma unroll
  for (int mt = 0; mt < 4; ++mt)
#pragma unroll
    for (int reg = 0; reg < 4; ++reg) {
      const int brow = mt*16 + kg*4 + reg;
      gp[(size_t)brow*1536 + g] = acc[mt][reg];
    }
}

// ---------------------------------------------------------------------------
// Kernel C2: GRU pointwise.
// ---------------------------------------------------------------------------
__global__ __launch_bounds__(512) void gru_pointwise(
    const float* __restrict__ gates, const float* __restrict__ hprev,
    const float* __restrict__ b_ih, const float* __restrict__ b_hh,
    float* __restrict__ hid_out, __hip_bfloat16* __restrict__ featb)
{
  const int b = blockIdx.x, j = threadIdx.x;
  const float* g0 = gates + (size_t)b*1536;
  const float* g1 = gates + (size_t)(BB + b)*1536;
  const float* g2 = gates + (size_t)(2*BB + b)*1536;

  const float i_r = g0[j]        + g1[j];
  const float i_z = g0[HH + j]   + g1[HH + j];
  const float i_n = g0[2*HH + j] + g1[2*HH + j];

  const float r = 1.f/(1.f + __expf(-(i_r + g2[j] + b_ih[j] + b_hh[j])));
  const float z = 1.f/(1.f + __expf(-(i_z + g2[HH+j] + b_ih[HH+j] + b_hh[HH+j])));
  const float n = tanhf(i_n + b_ih[2*HH+j] + r*(g2[2*HH+j] + b_hh[2*HH+j]));
  const float hp = hprev[b*HH + j];
  const float hn = (1.f - z)*n + z*hp;
  hid_out[b*HH + j] = hn;
  featb[(size_t)b*KD + j] = (__hip_bfloat16)hn;
}

// ---------------------------------------------------------------------------
// Kernel D: logits = featb @ W_out^T + b_out. Register path, NO LDS.
// Rotating-register 1-deep prefetch: next k-step's W (2x float4) and A
// (4x bf16x8) are issued before the current MFMAs, so every iteration has
// ~2KB/wave of W in flight. 12 waves/CU x 2KB >> 9.2KB needed to hide
// 900-cycle HBM latency at the per-CU BW share.
// ---------------------------------------------------------------------------
__global__ __launch_bounds__(256) void logits_gemm(
    const __hip_bfloat16* __restrict__ featb, const float* __restrict__ W_out,
    const float* __restrict__ b_out, float* __restrict__ out)
{
  const int w = threadIdx.x >> 6, lane = threadIdx.x & 63;
  const int col = lane & 15, kg = lane >> 4;
  const int v = blockIdx.x*64 + w*16 + col;
  const int vc = (v < VV) ? v : (VV - 1);

  const float* wp = W_out + (size_t)vc*KD + kg*8;
  const __hip_bfloat16* fp = featb + (size_t)col*KD + kg*8;

  f32x4 acc[4];
#pragma unroll
  for (int mt = 0; mt < 4; ++mt) acc[mt] = (f32x4){0.f,0.f,0.f,0.f};

  // current-stage registers
  float4 wa = *(const float4*)(wp);
  float4 wb = *(const float4*)(wp + 4);
  bf16x8 a0 = *(const bf16x8*)(fp);
  bf16x8 a1 = *(const bf16x8*)(fp + 16*KD);
  bf16x8 a2 = *(const bf16x8*)(fp + 32*KD);
  bf16x8 a3 = *(const bf16x8*)(fp + 48*KD);

  for (int k0 = 0; k0 < KD; k0 += 32) {
    // branchless prefetch of next k-step (last iter re-loads k=0, discarded)
    const int kn = (k0 + 32 < KD) ? (k0 + 32) : 0;
    const float4 nwa = *(const float4*)(wp + kn);
    const float4 nwb = *(const float4*)(wp + kn + 4);
    const bf16x8 n0 = *(const bf16x8*)(fp + kn);
    const bf16x8 n1 = *(const bf16x8*)(fp + 16*KD + kn);
    const bf16x8 n2 = *(const bf16x8*)(fp + 32*KD + kn);
    const bf16x8 n3 = *(const bf16x8*)(fp + 48*KD + kn);

    const bf16x8 bf = cvt8(wa, wb);
    acc[0] = __builtin_amdgcn_mfma_f32_16x16x32_bf16(a0, bf, acc[0], 0, 0, 0);
    acc[1] = __builtin_amdgcn_mfma_f32_16x16x32_bf16(a1, bf, acc[1], 0, 0, 0);
    acc[2] = __builtin_amdgcn_mfma_f32_16x16x32_bf16(a2, bf, acc[2], 0, 0, 0);
    acc[3] = __builtin_amdgcn_mfma_f32_16x16x32_bf16(a3, bf, acc[3], 0, 0, 0);

    wa = nwa; wb = nwb; a0 = n0; a1 = n1; a2 = n2; a3 = n3;
  }

  if (v < VV) {
    const float bo = b_out[v];
#pragma unroll
    for (int mt = 0; mt < 4; ++mt)
#pragma unroll
      for (int reg = 0; reg < 4; ++reg) {
        const int brow = mt*16 + kg*4 + reg;
        out[(size_t)brow*VV + v] = acc[mt][reg] + bo;
      }
  }
}

// ---------------------------------------------------------------------------
// Kernel E1: per-(row,chunk) max/expsum, two-pass in registers.
// ---------------------------------------------------------------------------
__global__ __launch_bounds__(256) void lsm_partial(
    const float* __restrict__ out, float* __restrict__ pm2, float* __restrict__ pl2)
{
  const int b = blockIdx.x >> 3, ch = blockIdx.x & (LCH-1);
  const int t = threadIdx.x;
  const float* p = out + (size_t)b*VV;
  const int beg = ch*(256*LPT);

  float r[LPT];
#pragma unroll
  for (int i = 0; i < LPT; ++i) {
    const int idx = beg + t + i*256;
    r[i] = (idx < VV) ? p[idx] : -INFINITY;
  }
  float m = r[0];
#pragma unroll
  for (int i = 1; i < LPT; ++i) m = fmaxf(m, r[i]);
  float l = 0.f;
#pragma unroll
  for (int i = 0; i < LPT; ++i) l += __expf(r[i] - m);

#pragma unroll
  for (int off = 32; off >= 1; off >>= 1) {
    const float m2 = __shfl_xor(m, off, 64), l2 = __shfl_xor(l, off, 64);
    const float mn = fmaxf(m, m2);
    l = l*__expf(m - mn) + l2*__expf(m2 - mn);
    m = mn;
  }
  __shared__ float sm[4], sl[4];
  const int w = t >> 6, lane = t & 63;
  if (lane == 0) { sm[w] = m; sl[w] = l; }
  __syncthreads();
  if (t == 0) {
    float M = sm[0], L = sl[0];
#pragma unroll
    for (int q = 1; q < 4; ++q) {
      const float mn = fmaxf(M, sm[q]);
      L = L*__expf(M - mn) + sl[q]*__expf(sm[q] - mn);
      M = mn;
    }
    pm2[blockIdx.x] = M; pl2[blockIdx.x] = L;
  }
}

// ---------------------------------------------------------------------------
// Kernel E2: logits -= c[row]; c from the 8 partials.
// ---------------------------------------------------------------------------
__global__ __launch_bounds__(256) void lsm_sub(
    float* __restrict__ out, const float* __restrict__ pm2,
    const float* __restrict__ pl2)
{
  const int t = threadIdx.x;
  const size_t off = (size_t)blockIdx.x * 1024;
  const size_t total = (size_t)BB*VV;
  __shared__ float cs[2];
  __shared__ int rowA_s;
  if (t < 2) {
    size_t pos = (t == 0) ? off : (off + 1023 < total ? off + 1023 : total - 1);
    const int row = (int)(pos / VV);
    float M = -INFINITY, L = 0.f;
#pragma unroll
    for (int q = 0; q < LCH; ++q) {
      const float mq = pm2[row*LCH + q], lq = pl2[row*LCH + q];
      const float mn = fmaxf(M, mq);
      L = L*__expf(M - mn) + lq*__expf(mq - mn);
      M = mn;
    }
    cs[t] = M + logf(L);
    if (t == 0) rowA_s = row;
  }
  __syncthreads();

  const size_t i = off + (size_t)t*4;
  if (i >= total) return;
  const size_t rs = (size_t)(rowA_s + 1)*VV;
  float4 v = *(float4*)(out + i);
  v.x -= (i     >= rs) ? cs[1] : cs[0];
  v.y -= (i + 1 >= rs) ? cs[1] : cs[0];
  v.z -= (i + 2 >= rs) ? cs[1] : cs[0];
  v.w -= (i + 3 >= rs) ? cs[1] : cs[0];
  *(float4*)(out + i) = v;
}

// ---------------------------------------------------------------------------
extern "C" void kernel_launch(void* const* d_in, const int* in_sizes, int n_in,
                              void* d_out, int out_size, void* d_ws, size_t ws_size,
                              hipStream_t stream)
{
  const int*   last_output = (const int*)d_in[0];
  const float* last_hidden = (const float*)d_in[1];
  const float* enc         = (const float*)d_in[2];
  const float* emb         = (const float*)d_in[3];
  const float* W_ih        = (const float*)d_in[4];
  const float* b_ih        = (const float*)d_in[5];
  const float* W_hh        = (const float*)d_in[6];
  const float* b_hh        = (const float*)d_in[7];
  const float* W_out       = (const float*)d_in[8];
  const float* b_out       = (const float*)d_in[9];
  float* out = (float*)d_out;

  __hip_bfloat16* featb = (__hip_bfloat16*)d_ws;            // 64x1024 bf16
  float* gates = (float*)((char*)d_ws + (size_t)BB*KD*2);   // 3x64x1536 f32
  float* pm   = gates + (size_t)3*BB*1536;
  float* pl   = pm + BB*NSPLIT;
  float* pm2  = pl + BB*NSPLIT;
  float* pl2  = pm2 + BB*LCH;
  float* pacc = out;  // 4 MB parked in dead logits region

  float* logits  = out;
  float* hid_out = out + (size_t)BB*VV;

  attn_partial <<<dim3(BB*NSPLIT), dim3(256), 0, stream>>>(last_hidden, enc, pm, pl, pacc);
  attn_reduce  <<<dim3(BB),        dim3(256), 0, stream>>>(pm, pl, pacc, featb);
  gru_gemm     <<<dim3(24*3),      dim3(256), 0, stream>>>(last_output, emb, last_hidden,
                                                           featb, W_ih, W_hh, gates);
  gru_pointwise<<<dim3(BB),        dim3(512), 0, stream>>>(gates, last_hidden, b_ih, b_hh,
                                                           hid_out, featb);
  logits_gemm  <<<dim3((VV+63)/64), dim3(256), 0, stream>>>(featb, W_out, b_out, logits);
  lsm_partial  <<<dim3(BB*LCH),    dim3(256), 0, stream>>>(logits, pm2, pl2);
  lsm_sub      <<<dim3((int)(((size_t)BB*VV + 1023)/1024)), dim3(256), 0, stream>>>(logits, pm2, pl2);
}

// Round 6
// 195.386 us; speedup vs baseline: 1.5069x; 1.1005x over previous
//
#include <hip/hip_runtime.h>
#include <hip/hip_bf16.h>
#include <math.h>

#define BB 64
#define SS 2048
#define HH 512
#define VV 50257
#define KD 1024   // I + H
#define NSPLIT 32 // attn s-chunks per batch row
#define LCH 8     // log-softmax chunks per row
#define LPT 25    // elems per thread in lsm_partial

typedef float f32x4 __attribute__((ext_vector_type(4)));
typedef __bf16 bf16x8 __attribute__((ext_vector_type(8)));

__device__ __forceinline__ float dot4(float4 a, float4 b) {
  return a.x*b.x + a.y*b.y + a.z*b.z + a.w*b.w;
}

__device__ __forceinline__ bf16x8 cvt8(float4 a, float4 b) {
  bf16x8 r;
  r[0]=(__bf16)a.x; r[1]=(__bf16)a.y; r[2]=(__bf16)a.z; r[3]=(__bf16)a.w;
  r[4]=(__bf16)b.x; r[5]=(__bf16)b.y; r[6]=(__bf16)b.z; r[7]=(__bf16)b.w;
  return r;
}

// featA fragment-linear layout: element (b, k) lives at
//   (k>>5)*2048 + (b>>4)*512 + ((k>>3)&3)*128 + (b&15)*8 + (k&7)
// so a wave's MFMA A-fragment load (lane = kg*16+col, 8 elems) is a fully
// contiguous 1KB dwordx4 load: featA + kc*2048 + mt*512 + lane*8.
__device__ __forceinline__ size_t fragAddr(int b, int k) {
  return (size_t)(k >> 5)*2048 + (size_t)(b >> 4)*512
       + (size_t)((k >> 3) & 3)*128 + (size_t)(b & 15)*8 + (size_t)(k & 7);
}

// ---------------------------------------------------------------------------
// Kernel A: fused scores+softmax+context partials. Group-of-4 online softmax.
// Group loop NOT unrolled -> e-regs live one group at a time -> low VGPR,
// high occupancy; TLP hides HBM latency.
// ---------------------------------------------------------------------------
__global__ __launch_bounds__(256) void attn_partial(
    const float* __restrict__ hprev, const float* __restrict__ enc,
    float* __restrict__ pm, float* __restrict__ pl, float* __restrict__ pacc)
{
  const int b = blockIdx.x >> 5;
  const int split = blockIdx.x & 31;
  const int t = threadIdx.x;
  const int w = t >> 6, lane = t & 63;

  const float* hb = hprev + b*HH + lane*8;
  const float4 h0 = *(const float4*)hb;
  const float4 h1 = *(const float4*)(hb + 4);

  float m = -INFINITY, lsum = 0.f;
  float acc[8];
#pragma unroll
  for (int j = 0; j < 8; ++j) acc[j] = 0.f;

  const int s0 = split*64 + w*16;
#pragma unroll 1
  for (int g = 0; g < 4; ++g) {
    const float* ep0 = enc + ((size_t)(s0 + g*4 + 0)*BB + b)*HH + lane*8;
    const float* ep1 = enc + ((size_t)(s0 + g*4 + 1)*BB + b)*HH + lane*8;
    const float* ep2 = enc + ((size_t)(s0 + g*4 + 2)*BB + b)*HH + lane*8;
    const float* ep3 = enc + ((size_t)(s0 + g*4 + 3)*BB + b)*HH + lane*8;
    const float4 e0a = *(const float4*)ep0, e0b = *(const float4*)(ep0+4);
    const float4 e1a = *(const float4*)ep1, e1b = *(const float4*)(ep1+4);
    const float4 e2a = *(const float4*)ep2, e2b = *(const float4*)(ep2+4);
    const float4 e3a = *(const float4*)ep3, e3b = *(const float4*)(ep3+4);

    float d0 = dot4(h0,e0a) + dot4(h1,e0b);
    float d1 = dot4(h0,e1a) + dot4(h1,e1b);
    float d2 = dot4(h0,e2a) + dot4(h1,e2b);
    float d3 = dot4(h0,e3a) + dot4(h1,e3b);
#pragma unroll
    for (int off = 32; off >= 1; off >>= 1) {
      d0 += __shfl_xor(d0, off, 64);
      d1 += __shfl_xor(d1, off, 64);
      d2 += __shfl_xor(d2, off, 64);
      d3 += __shfl_xor(d3, off, 64);
    }
    const float gm = fmaxf(fmaxf(d0,d1), fmaxf(d2,d3));
    const float mn = fmaxf(m, gm);
    const float sc = __expf(m - mn);
    const float p0 = __expf(d0 - mn), p1 = __expf(d1 - mn);
    const float p2 = __expf(d2 - mn), p3 = __expf(d3 - mn);
    lsum = lsum*sc + ((p0+p1) + (p2+p3));
    acc[0] = acc[0]*sc + p0*e0a.x + p1*e1a.x + p2*e2a.x + p3*e3a.x;
    acc[1] = acc[1]*sc + p0*e0a.y + p1*e1a.y + p2*e2a.y + p3*e3a.y;
    acc[2] = acc[2]*sc + p0*e0a.z + p1*e1a.z + p2*e2a.z + p3*e3a.z;
    acc[3] = acc[3]*sc + p0*e0a.w + p1*e1a.w + p2*e2a.w + p3*e3a.w;
    acc[4] = acc[4]*sc + p0*e0b.x + p1*e1b.x + p2*e2b.x + p3*e3b.x;
    acc[5] = acc[5]*sc + p0*e0b.y + p1*e1b.y + p2*e2b.y + p3*e3b.y;
    acc[6] = acc[6]*sc + p0*e0b.z + p1*e1b.z + p2*e2b.z + p3*e3b.z;
    acc[7] = acc[7]*sc + p0*e0b.w + p1*e1b.w + p2*e2b.w + p3*e3b.w;
    m = mn;
  }

  __shared__ float sm4[4], sl4[4];
  __shared__ float sacc[4][HH];
  if (lane == 0) { sm4[w] = m; sl4[w] = lsum; }
  __syncthreads();
  const float M = fmaxf(fmaxf(sm4[0], sm4[1]), fmaxf(sm4[2], sm4[3]));
  const float ew = __expf(m - M);
#pragma unroll
  for (int j = 0; j < 8; ++j) sacc[w][lane*8 + j] = acc[j]*ew;
  __syncthreads();

  const int rec = blockIdx.x;
  for (int hh = t; hh < HH; hh += 256)
    pacc[(size_t)rec*HH + hh] = sacc[0][hh]+sacc[1][hh]+sacc[2][hh]+sacc[3][hh];
  if (t == 0) {
    float L = sl4[0]*__expf(sm4[0]-M) + sl4[1]*__expf(sm4[1]-M)
            + sl4[2]*__expf(sm4[2]-M) + sl4[3]*__expf(sm4[3]-M);
    pm[rec] = M; pl[rec] = L;
  }
}

// ---------------------------------------------------------------------------
// Kernel B: combine NSPLIT partials per b -> context -> featA (fragment order)
// ---------------------------------------------------------------------------
__global__ __launch_bounds__(256) void attn_reduce(
    const float* __restrict__ pm, const float* __restrict__ pl,
    const float* __restrict__ pacc, __hip_bfloat16* __restrict__ featA)
{
  const int b = blockIdx.x, t = threadIdx.x;
  __shared__ float smm[NSPLIT], sll[NSPLIT], sco[NSPLIT];
  if (t < NSPLIT) { smm[t] = pm[b*NSPLIT + t]; sll[t] = pl[b*NSPLIT + t]; }
  __syncthreads();
  float M = -INFINITY;
  for (int q = 0; q < NSPLIT; ++q) M = fmaxf(M, smm[q]);
  float L = 0.f;
  for (int q = 0; q < NSPLIT; ++q) L += sll[q]*__expf(smm[q]-M);
  const float inv = 1.f/L;
  if (t < NSPLIT) sco[t] = __expf(smm[t]-M)*inv;
  __syncthreads();
  // thread t handles hh = 2t, 2t+1 (context occupies k = 512+hh)
  const int hh0 = 2*t;
  float s0 = 0.f, s1 = 0.f;
  for (int q = 0; q < NSPLIT; ++q) {
    const float* pq = pacc + ((size_t)b*NSPLIT + q)*HH;
    s0 += pq[hh0]   * sco[q];
    s1 += pq[hh0+1] * sco[q];
  }
  const size_t a = fragAddr(b, HH + hh0);   // hh0 even -> a+1 is same 8-run
  featA[a]   = (__hip_bfloat16)s0;
  featA[a+1] = (__hip_bfloat16)s1;
}

// ---------------------------------------------------------------------------
// Kernel C: GRU gates as MFMA GEMM (3 source segments). Weights read once.
// ---------------------------------------------------------------------------
__global__ __launch_bounds__(256) void gru_gemm(
    const int* __restrict__ last_out, const float* __restrict__ emb,
    const float* __restrict__ hprev, const __hip_bfloat16* __restrict__ featA,
    const float* __restrict__ W_ih, const float* __restrict__ W_hh,
    float* __restrict__ gates)  // [3][BB][1536]
{
  const int gt  = blockIdx.x / 3;
  const int seg = blockIdx.x % 3;
  const int w = threadIdx.x >> 6, lane = threadIdx.x & 63;
  const int col = lane & 15, kg = lane >> 4;
  const int g = gt*64 + w*16 + col;

  const float* wrow = (seg == 2) ? (W_hh + (size_t)g*HH)
                                 : (W_ih + (size_t)g*KD + seg*HH);

  int lo_r[4];
#pragma unroll
  for (int mt = 0; mt < 4; ++mt) lo_r[mt] = last_out[mt*16 + col];

  f32x4 acc[4];
#pragma unroll
  for (int mt = 0; mt < 4; ++mt) acc[mt] = (f32x4){0.f,0.f,0.f,0.f};

  for (int k0 = 0; k0 < HH; k0 += 32) {
    const float* wp = wrow + k0 + kg*8;
    const bf16x8 bf = cvt8(*(const float4*)wp, *(const float4*)(wp+4));
#pragma unroll
    for (int mt = 0; mt < 4; ++mt) {
      const int bb = mt*16 + col;
      bf16x8 af;
      if (seg == 0) {
        const float* ap = emb + (size_t)lo_r[mt]*HH + k0 + kg*8;
        af = cvt8(*(const float4*)ap, *(const float4*)(ap+4));
      } else if (seg == 1) {
        // context at k_global = 512 + k0 + kg*8 (8-aligned run)
        af = *(const bf16x8*)(featA + fragAddr(bb, HH + k0 + kg*8));
      } else {
        const float* ap = hprev + (size_t)bb*HH + k0 + kg*8;
        af = cvt8(*(const float4*)ap, *(const float4*)(ap+4));
      }
      acc[mt] = __builtin_amdgcn_mfma_f32_16x16x32_bf16(af, bf, acc[mt], 0, 0, 0);
    }
  }

  float* gp = gates + (size_t)seg*BB*1536;
#pragma unroll
  for (int mt = 0; mt < 4; ++mt)
#pragma unroll
    for (int reg = 0; reg < 4; ++reg) {
      const int brow = mt*16 + kg*4 + reg;
      gp[(size_t)brow*1536 + g] = acc[mt][reg];
    }
}

// ---------------------------------------------------------------------------
// Kernel C2: GRU pointwise -> hid_out (f32) + featA (fragment order, k=j).
// ---------------------------------------------------------------------------
__global__ __launch_bounds__(512) void gru_pointwise(
    const float* __restrict__ gates, const float* __restrict__ hprev,
    const float* __restrict__ b_ih, const float* __restrict__ b_hh,
    float* __restrict__ hid_out, __hip_bfloat16* __restrict__ featA)
{
  const int b = blockIdx.x, j = threadIdx.x;
  const float* g0 = gates + (size_t)b*1536;
  const float* g1 = gates + (size_t)(BB + b)*1536;
  const float* g2 = gates + (size_t)(2*BB + b)*1536;

  const float i_r = g0[j]        + g1[j];
  const float i_z = g0[HH + j]   + g1[HH + j];
  const float i_n = g0[2*HH + j] + g1[2*HH + j];

  const float r = 1.f/(1.f + __expf(-(i_r + g2[j] + b_ih[j] + b_hh[j])));
  const float z = 1.f/(1.f + __expf(-(i_z + g2[HH+j] + b_ih[HH+j] + b_hh[HH+j])));
  const float n = tanhf(i_n + b_ih[2*HH+j] + r*(g2[2*HH+j] + b_hh[2*HH+j]));
  const float hp = hprev[b*HH + j];
  const float hn = (1.f - z)*n + z*hp;
  hid_out[b*HH + j] = hn;
  featA[fragAddr(b, j)] = (__hip_bfloat16)hn;
}

// ---------------------------------------------------------------------------
// Kernel D: logits = feat @ W_out^T + b_out. Register path, NO LDS.
// A-fragments now fully coalesced 1KB loads from featA (fragment-linear).
// 1-deep rotating prefetch keeps W + A in flight across the MFMA block.
// ---------------------------------------------------------------------------
__global__ __launch_bounds__(256) void logits_gemm(
    const __hip_bfloat16* __restrict__ featA, const float* __restrict__ W_out,
    const float* __restrict__ b_out, float* __restrict__ out)
{
  const int w = threadIdx.x >> 6, lane = threadIdx.x & 63;
  const int col = lane & 15, kg = lane >> 4;
  const int v = blockIdx.x*64 + w*16 + col;
  const int vc = (v < VV) ? v : (VV - 1);

  const float* wp = W_out + (size_t)vc*KD + kg*8;
  const __hip_bfloat16* fp = featA + lane*8;   // + kc*2048 + mt*512

  f32x4 acc[4];
#pragma unroll
  for (int mt = 0; mt < 4; ++mt) acc[mt] = (f32x4){0.f,0.f,0.f,0.f};

  float4 wa = *(const float4*)(wp);
  float4 wb = *(const float4*)(wp + 4);
  bf16x8 a0 = *(const bf16x8*)(fp);
  bf16x8 a1 = *(const bf16x8*)(fp + 512);
  bf16x8 a2 = *(const bf16x8*)(fp + 1024);
  bf16x8 a3 = *(const bf16x8*)(fp + 1536);

  for (int k0 = 0; k0 < KD; k0 += 32) {
    const int kn = (k0 + 32 < KD) ? (k0 + 32) : 0;
    const float4 nwa = *(const float4*)(wp + kn);
    const float4 nwb = *(const float4*)(wp + kn + 4);
    const __hip_bfloat16* fn = fp + (kn >> 5)*2048;
    const bf16x8 n0 = *(const bf16x8*)(fn);
    const bf16x8 n1 = *(const bf16x8*)(fn + 512);
    const bf16x8 n2 = *(const bf16x8*)(fn + 1024);
    const bf16x8 n3 = *(const bf16x8*)(fn + 1536);

    const bf16x8 bf = cvt8(wa, wb);
    acc[0] = __builtin_amdgcn_mfma_f32_16x16x32_bf16(a0, bf, acc[0], 0, 0, 0);
    acc[1] = __builtin_amdgcn_mfma_f32_16x16x32_bf16(a1, bf, acc[1], 0, 0, 0);
    acc[2] = __builtin_amdgcn_mfma_f32_16x16x32_bf16(a2, bf, acc[2], 0, 0, 0);
    acc[3] = __builtin_amdgcn_mfma_f32_16x16x32_bf16(a3, bf, acc[3], 0, 0, 0);

    wa = nwa; wb = nwb; a0 = n0; a1 = n1; a2 = n2; a3 = n3;
  }

  if (v < VV) {
    const float bo = b_out[v];
#pragma unroll
    for (int mt = 0; mt < 4; ++mt)
#pragma unroll
      for (int reg = 0; reg < 4; ++reg) {
        const int brow = mt*16 + kg*4 + reg;
        out[(size_t)brow*VV + v] = acc[mt][reg] + bo;
      }
  }
}

// ---------------------------------------------------------------------------
// Kernel E1: per-(row,chunk) max/expsum, two-pass in registers.
// ---------------------------------------------------------------------------
__global__ __launch_bounds__(256) void lsm_partial(
    const float* __restrict__ out, float* __restrict__ pm2, float* __restrict__ pl2)
{
  const int b = blockIdx.x >> 3, ch = blockIdx.x & (LCH-1);
  const int t = threadIdx.x;
  const float* p = out + (size_t)b*VV;
  const int beg = ch*(256*LPT);

  float r[LPT];
#pragma unroll
  for (int i = 0; i < LPT; ++i) {
    const int idx = beg + t + i*256;
    r[i] = (idx < VV) ? p[idx] : -INFINITY;
  }
  float m = r[0];
#pragma unroll
  for (int i = 1; i < LPT; ++i) m = fmaxf(m, r[i]);
  float l = 0.f;
#pragma unroll
  for (int i = 0; i < LPT; ++i) l += __expf(r[i] - m);

#pragma unroll
  for (int off = 32; off >= 1; off >>= 1) {
    const float m2 = __shfl_xor(m, off, 64), l2 = __shfl_xor(l, off, 64);
    const float mn = fmaxf(m, m2);
    l = l*__expf(m - mn) + l2*__expf(m2 - mn);
    m = mn;
  }
  __shared__ float sm[4], sl[4];
  const int w = t >> 6, lane = t & 63;
  if (lane == 0) { sm[w] = m; sl[w] = l; }
  __syncthreads();
  if (t == 0) {
    float M = sm[0], L = sl[0];
#pragma unroll
    for (int q = 1; q < 4; ++q) {
      const float mn = fmaxf(M, sm[q]);
      L = L*__expf(M - mn) + sl[q]*__expf(sm[q] - mn);
      M = mn;
    }
    pm2[blockIdx.x] = M; pl2[blockIdx.x] = L;
  }
}

// ---------------------------------------------------------------------------
// Kernel E2: logits -= c[row]; c from the 8 partials.
// ---------------------------------------------------------------------------
__global__ __launch_bounds__(256) void lsm_sub(
    float* __restrict__ out, const float* __restrict__ pm2,
    const float* __restrict__ pl2)
{
  const int t = threadIdx.x;
  const size_t off = (size_t)blockIdx.x * 1024;
  const size_t total = (size_t)BB*VV;
  __shared__ float cs[2];
  __shared__ int rowA_s;
  if (t < 2) {
    size_t pos = (t == 0) ? off : (off + 1023 < total ? off + 1023 : total - 1);
    const int row = (int)(pos / VV);
    float M = -INFINITY, L = 0.f;
#pragma unroll
    for (int q = 0; q < LCH; ++q) {
      const float mq = pm2[row*LCH + q], lq = pl2[row*LCH + q];
      const float mn = fmaxf(M, mq);
      L = L*__expf(M - mn) + lq*__expf(mq - mn);
      M = mn;
    }
    cs[t] = M + logf(L);
    if (t == 0) rowA_s = row;
  }
  __syncthreads();

  const size_t i = off + (size_t)t*4;
  if (i >= total) return;
  const size_t rs = (size_t)(rowA_s + 1)*VV;
  float4 v = *(float4*)(out + i);
  v.x -= (i     >= rs) ? cs[1] : cs[0];
  v.y -= (i + 1 >= rs) ? cs[1] : cs[0];
  v.z -= (i + 2 >= rs) ? cs[1] : cs[0];
  v.w -= (i + 3 >= rs) ? cs[1] : cs[0];
  *(float4*)(out + i) = v;
}

// ---------------------------------------------------------------------------
extern "C" void kernel_launch(void* const* d_in, const int* in_sizes, int n_in,
                              void* d_out, int out_size, void* d_ws, size_t ws_size,
                              hipStream_t stream)
{
  const int*   last_output = (const int*)d_in[0];
  const float* last_hidden = (const float*)d_in[1];
  const float* enc         = (const float*)d_in[2];
  const float* emb         = (const float*)d_in[3];
  const float* W_ih        = (const float*)d_in[4];
  const float* b_ih        = (const float*)d_in[5];
  const float* W_hh        = (const float*)d_in[6];
  const float* b_hh        = (const float*)d_in[7];
  const float* W_out       = (const float*)d_in[8];
  const float* b_out       = (const float*)d_in[9];
  float* out = (float*)d_out;

  __hip_bfloat16* featA = (__hip_bfloat16*)d_ws;            // 64x1024 bf16, fragment order
  float* gates = (float*)((char*)d_ws + (size_t)BB*KD*2);   // 3x64x1536 f32
  float* pm   = gates + (size_t)3*BB*1536;
  float* pl   = pm + BB*NSPLIT;
  float* pm2  = pl + BB*NSPLIT;
  float* pl2  = pm2 + BB*LCH;
  float* pacc = out;  // 4 MB parked in dead logits region

  float* logits  = out;
  float* hid_out = out + (size_t)BB*VV;

  attn_partial <<<dim3(BB*NSPLIT), dim3(256), 0, stream>>>(last_hidden, enc, pm, pl, pacc);
  attn_reduce  <<<dim3(BB),        dim3(256), 0, stream>>>(pm, pl, pacc, featA);
  gru_gemm     <<<dim3(24*3),      dim3(256), 0, stream>>>(last_output, emb, last_hidden,
                                                           featA, W_ih, W_hh, gates);
  gru_pointwise<<<dim3(BB),        dim3(512), 0, stream>>>(gates, last_hidden, b_ih, b_hh,
                                                           hid_out, featA);
  logits_gemm  <<<dim3((VV+63)/64), dim3(256), 0, stream>>>(featA, W_out, b_out, logits);
  lsm_partial  <<<dim3(BB*LCH),    dim3(256), 0, stream>>>(logits, pm2, pl2);
  lsm_sub      <<<dim3((int)(((size_t)BB*VV + 1023)/1024)), dim3(256), 0, stream>>>(logits, pm2, pl2);
}